// Round 3
// baseline (430.774 us; speedup 1.0000x reference)
//
#include <hip/hip_runtime.h>
#include <hip/hip_bf16.h>
#include <stdint.h>

// BcosGCNLayer: out[n,o] = lin * |lin| / (R_n * C_o),  lin = z @ W^T
//   R_n = max(||z_n||, eps), C_o = max(||w_o||, eps), eps = 1e-12
// z: [M,512] fp32, W: [512,512] fp32, out: [M,512] fp32.
//
// V4: block = 64 rows x 256 cols, 256 threads = 4 waves (wave w: cols 64w..64w+63).
// Small LDS (43.5 KB) -> 3 blocks/CU for cross-block TLP. A streamed in 32-k
// chunks (fp32 load -> sumsq -> bf16 -> LDS, 80B-padded rows) inside the K-loop;
// B chunks DMA'd via global_load_lds with counted vmcnt(6), depth-2. Row norms
// reduced once after the K-loop. W pre-transposed to [chunk][k8][col] granules.

constexpr int KDIM = 512;
constexpr int NDIM = 512;

typedef __attribute__((ext_vector_type(8))) short bf16x8;   // MFMA A/B frag (4 VGPR)
typedef __attribute__((ext_vector_type(4))) float f32x4;    // MFMA C/D frag
typedef __attribute__((ext_vector_type(4))) uint32_t u32x4; // 16B LDS store

__device__ __forceinline__ uint32_t pk_bf16(float a, float b) {
  __hip_bfloat162 h = __float22bfloat162_rn(make_float2(a, b));
  union { __hip_bfloat162 h2; uint32_t u; } c;
  c.h2 = h;
  return c.u;  // low 16 = a, high 16 = b
}

__device__ __forceinline__ void gload_lds16(const void* g, void* lds) {
  // async global->LDS DMA, 16B/lane; LDS dest = wave-uniform base + lane*16.
  __builtin_amdgcn_global_load_lds(
      (const __attribute__((address_space(1))) uint32_t*)(uintptr_t)g,
      (__attribute__((address_space(3))) uint32_t*)(uintptr_t)lds,
      16, 0, 0);
}

// ---------- prep: W fp32 -> bf16 transposed-granule layout + 1/max(||w_o||,eps) ----
// granule g of chunk c (granule = 8 bf16 = 16 B): g = k8*512 + col, k8=0..3
//   wbt[(c*2048 + g)*8 .. +8] = W_bf16[col][c*32 + k8*8 .. +8]
__global__ __launch_bounds__(128) void prep_w(const float* __restrict__ w,
                                              unsigned short* __restrict__ wbt,
                                              float* __restrict__ cninv) {
  const int row = blockIdx.x;   // 0..511 (the B "col")
  const int t   = threadIdx.x;  // 0..127, 4 floats each
  const int k0  = t * 4;
  f32x4 v = *(const f32x4*)(w + (size_t)row * KDIM + k0);
  float s = v.x * v.x + v.y * v.y + v.z * v.z + v.w * v.w;

  uint2 p;
  p.x = pk_bf16(v.x, v.y);
  p.y = pk_bf16(v.z, v.w);
  const int c  = k0 >> 5;
  const int k8 = (k0 >> 3) & 3;
  *(uint2*)(wbt + ((size_t)c * 2048 + k8 * 512 + row) * 8 + (k0 & 7)) = p;

  #pragma unroll
  for (int off = 32; off > 0; off >>= 1) s += __shfl_down(s, off, 64);
  __shared__ float red[2];
  if ((t & 63) == 0) red[t >> 6] = s;
  __syncthreads();
  if (t == 0) cninv[row] = 1.0f / fmaxf(sqrtf(red[0] + red[1]), 1e-12f);
}

// ---------- main fused GEMM ----------
__global__ __launch_bounds__(256, 3) void gemm_bcos(const float* __restrict__ z,
                                                    const unsigned short* __restrict__ wbt,
                                                    const float* __restrict__ cninv,
                                                    float* __restrict__ out, int M) {
  __shared__ unsigned short As[2][64 * 40];   // [64 rows][40 elems], 80 B row stride
  __shared__ unsigned short Bs[2][1024 * 8];  // 16 KiB per buffer, [k8][256 cols] granules
  __shared__ float rowsq[64];
  __shared__ float rinv_s[64];

  const int t    = threadIdx.x;    // 0..255
  const int w    = t >> 6;         // wave 0..3
  const int lane = t & 63;
  const int lrow = lane & 15;      // frag row/col index
  const int quad = lane >> 4;      // k-sub select; C row base = quad*4
  const int nb   = blockIdx.x;     // 0..1 col-half
  const int mb   = blockIdx.y;
  const int wn   = w * 64;         // col base within this half

  // A-staging coords: thread t -> row t>>2, 8 floats at seg (t&3)*8 per chunk
  const int arow = t >> 2;
  const int aseg = t & 3;
  int rg = mb * 64 + arow;
  if (rg >= M) rg = M - 1;         // tail clamp (stores are guarded)
  const float* zrow = z + (size_t)rg * KDIM + aseg * 8;
  char* const adst0 = (char*)As[0] + arow * 80 + aseg * 16;
  char* const adst1 = (char*)As[1] + arow * 80 + aseg * 16;

  float sq = 0.0f;

  // ---- prologue: issue A(0), A(1), B(0), B(1) ----
  f32x4 a0A = *(const f32x4*)(zrow + 0);
  f32x4 a1A = *(const f32x4*)(zrow + 4);
  f32x4 a0B = *(const f32x4*)(zrow + 32);
  f32x4 a1B = *(const f32x4*)(zrow + 36);

  #pragma unroll
  for (int i = 0; i < 4; ++i) {
    const int gl = t + 256 * i;
    gload_lds16(wbt + ((size_t)(gl >> 8) * 512 + nb * 256 + (gl & 255)) * 8,
                &Bs[0][gl * 8]);
  }
  #pragma unroll
  for (int i = 0; i < 4; ++i) {
    const int gl = t + 256 * i;
    gload_lds16(wbt + ((size_t)2048 + (gl >> 8) * 512 + nb * 256 + (gl & 255)) * 8,
                &Bs[1][gl * 8]);
  }

  // convert + store A(0)
  {
    sq += a0A.x*a0A.x + a0A.y*a0A.y + a0A.z*a0A.z + a0A.w*a0A.w
        + a1A.x*a1A.x + a1A.y*a1A.y + a1A.z*a1A.z + a1A.w*a1A.w;
    u32x4 p;
    p.x = pk_bf16(a0A.x, a0A.y); p.y = pk_bf16(a0A.z, a0A.w);
    p.z = pk_bf16(a1A.x, a1A.y); p.w = pk_bf16(a1A.z, a1A.w);
    *(u32x4*)adst0 = p;
  }

  f32x4 acc[4][4];
  #pragma unroll
  for (int i = 0; i < 4; ++i)
    #pragma unroll
    for (int j = 0; j < 4; ++j) acc[i][j] = (f32x4)0.0f;

  asm volatile("s_waitcnt vmcnt(4)" ::: "memory");   // B(0) done (older A loads too)
  asm volatile("s_waitcnt lgkmcnt(0)" ::: "memory"); // A(0) ds_write drained
  __builtin_amdgcn_s_barrier();
  asm volatile("" ::: "memory");

  // ---- K loop: 16 chunks of BK=32; A reg->LDS and B DMA both double-buffered ----
  #pragma unroll
  for (int c = 0; c < 16; ++c) {
    bf16x8 bfr[4], afr[4];
    #pragma unroll
    for (int nt = 0; nt < 4; ++nt)
      bfr[nt] = *(const bf16x8*)&Bs[c & 1][(quad * 256 + wn + nt * 16 + lrow) * 8];
    #pragma unroll
    for (int mt = 0; mt < 4; ++mt)
      afr[mt] = *(const bf16x8*)((const char*)As[c & 1] + (mt * 16 + lrow) * 80 + quad * 16);

    __builtin_amdgcn_s_setprio(1);
    #pragma unroll
    for (int mt = 0; mt < 4; ++mt)
      #pragma unroll
      for (int nt = 0; nt < 4; ++nt)
        acc[mt][nt] = __builtin_amdgcn_mfma_f32_16x16x32_bf16(afr[mt], bfr[nt], acc[mt][nt], 0, 0, 0);
    __builtin_amdgcn_s_setprio(0);

    if (c < 15) {
      asm volatile("" ::: "memory");
      __builtin_amdgcn_s_barrier();            // all waves done with buffers [c&1]
      asm volatile("" ::: "memory");

      if (c + 2 < 16) {
        // issue A(c+2) into freed reg slot, B(c+2) into freed LDS buffer
        f32x4 n0 = *(const f32x4*)(zrow + (c + 2) * 32);
        f32x4 n1 = *(const f32x4*)(zrow + (c + 2) * 32 + 4);
        if ((c & 1) == 0) { a0A = n0; a1A = n1; } else { a0B = n0; a1B = n1; }
        #pragma unroll
        for (int i = 0; i < 4; ++i) {
          const int gl = t + 256 * i;
          gload_lds16(wbt + ((size_t)(c + 2) * 2048 + (gl >> 8) * 512 + nb * 256 + (gl & 255)) * 8,
                      &Bs[c & 1][gl * 8]);
        }
      }
      // convert + store A(c+1) (compiler waits only its own load; DMAs stay in flight)
      {
        f32x4 v0 = ((c & 1) == 0) ? a0B : a0A;
        f32x4 v1 = ((c & 1) == 0) ? a1B : a1A;
        sq += v0.x*v0.x + v0.y*v0.y + v0.z*v0.z + v0.w*v0.w
            + v1.x*v1.x + v1.y*v1.y + v1.z*v1.z + v1.w*v1.w;
        u32x4 p;
        p.x = pk_bf16(v0.x, v0.y); p.y = pk_bf16(v0.z, v0.w);
        p.z = pk_bf16(v1.x, v1.y); p.w = pk_bf16(v1.z, v1.w);
        *(u32x4*)(((c & 1) == 0) ? adst1 : adst0) = p;
      }

      // B(c+1) must be resident past this barrier; leave newer issues in flight.
      if (c + 2 < 16) asm volatile("s_waitcnt vmcnt(6)" ::: "memory");
      else            asm volatile("s_waitcnt vmcnt(0)" ::: "memory");
      asm volatile("s_waitcnt lgkmcnt(0)" ::: "memory");  // A(c+1) ds_write drained
      __builtin_amdgcn_s_barrier();
      asm volatile("" ::: "memory");
    }
  }

  // ---- row norms: 4 threads per row, lane-consecutive ----
  sq += __shfl_down(sq, 2, 64);
  sq += __shfl_down(sq, 1, 64);
  if (aseg == 0) rowsq[arow] = sq;
  __syncthreads();
  if (t < 64) rinv_s[t] = 1.0f / fmaxf(sqrtf(rowsq[t]), 1e-12f);
  __syncthreads();

  // ---- epilogue: out = v*|v| * Rinv * Cinv (C/D: col=lane&15, row=quad*4+reg) ----
  #pragma unroll
  for (int nt = 0; nt < 4; ++nt) {
    const int colg = nb * 256 + wn + nt * 16 + lrow;
    const float cv = cninv[colg];
    #pragma unroll
    for (int mt = 0; mt < 4; ++mt) {
      const int rl = mt * 16 + quad * 4;
      #pragma unroll
      for (int i = 0; i < 4; ++i) {
        const int rowg = mb * 64 + rl + i;
        if (rowg < M) {
          const float v = acc[mt][nt][i];
          __builtin_nontemporal_store(v * fabsf(v) * rinv_s[rl + i] * cv,
                                      &out[(size_t)rowg * NDIM + colg]);
        }
      }
    }
  }
}

extern "C" void kernel_launch(void* const* d_in, const int* in_sizes, int n_in,
                              void* d_out, int out_size, void* d_ws, size_t ws_size,
                              hipStream_t stream) {
  const float* z = (const float*)d_in[0];
  const float* w = (const float*)d_in[1];
  float* out = (float*)d_out;
  const int M = in_sizes[0] / KDIM;  // 100000

  unsigned short* wbt = (unsigned short*)d_ws;                    // 512 KB bf16, granule layout
  float* cninv = (float*)((char*)d_ws + (size_t)NDIM * KDIM * 2); // 512 fp32

  prep_w<<<dim3(NDIM), dim3(128), 0, stream>>>(w, wbt, cninv);

  dim3 grid(2, (M + 63) / 64);  // col-half fastest -> adjacent blocks share z rows (L2/L3)
  gemm_bcos<<<grid, dim3(256), 0, stream>>>(z, wbt, cninv, out, M);
}